// Round 4
// baseline (421.711 us; speedup 1.0000x reference)
//
#include <hip/hip_runtime.h>
#include <math.h>

// Problem constants (from reference)
#define B_ 16
#define T_ 4096
#define C_ 512
#define E_ 64
#define K_ 2048
#define N_ (B_*T_)          // 65536
#define ZQ_ELEMS 4194304    // B*E*T

typedef __attribute__((ext_vector_type(8))) short short8;
typedef __attribute__((ext_vector_type(4))) short short4v;
typedef __attribute__((ext_vector_type(4))) float f32x4;

// ws layout (bytes):
//   h_hi : [N][64] bf16 @ 0         (8 MB)
//   h_lo : [N][64] bf16 @ 8388608   (8 MB)
//   e_hi : [K][64] bf16 @ 16777216  (256 KB)   <- hist aliases head AFTER vq
//   e_lo : [K][64] bf16 @ 17039360  (256 KB)
//   nhcc : [K] f32      @ 17301504  (8 KB)     (-0.5*||e_k||^2)
//   w_hi : [64][512] bf16 @ 17309696 (64 KB)
//   w_lo : [64][512] bf16 @ 17375232 (64 KB)
//   keys : [N] u64      @ 17309696  (512 KB)   <- ALIASES w; memset 0xFF AFTER proj
//   loss : f32          @ 17833984  (4 B)
#define WS_HHI   0
#define WS_HLO   8388608
#define WS_EHI   16777216
#define WS_ELO   17039360
#define WS_NHCC  17301504
#define WS_WHI   17309696
#define WS_WLO   17375232
#define WS_KEYS  17309696
#define WS_HIST  16777216
#define WS_LOSS  17833984

struct HiLo { short hi, lo; };

__device__ __forceinline__ unsigned short rne16(float v) {
    unsigned u = __float_as_uint(v);
    return (unsigned short)((u + 0x7FFFu + ((u >> 16) & 1u)) >> 16);
}
// trunc-hi / rne-lo split: v ~= hi + lo (lo = v - trunc(v), exact by Sterbenz)
__device__ __forceinline__ HiLo split_tr(float v) {
    unsigned u = __float_as_uint(v);
    HiLo r;
    r.hi = (short)(u >> 16);
    float hf = __uint_as_float(u & 0xFFFF0000u);
    r.lo = (short)rne16(v - hf);
    return r;
}

// ---------------------------------------------------------------------------
// W split: W[64][512] fp32 -> w_hi/w_lo bf16 (flat). Grid 32 x 256.
// ---------------------------------------------------------------------------
__global__ void wprep_kernel(const float* __restrict__ W,
                             short* __restrict__ whi, short* __restrict__ wlo) {
    int idx = (blockIdx.x * 256 + threadIdx.x) * 4;
    float4 v = *(const float4*)(W + idx);
    short4v h, l;
    HiLo a = split_tr(v.x); h[0] = a.hi; l[0] = a.lo;
    HiLo b = split_tr(v.y); h[1] = b.hi; l[1] = b.lo;
    HiLo c = split_tr(v.z); h[2] = c.hi; l[2] = c.lo;
    HiLo d = split_tr(v.w); h[3] = d.hi; l[3] = d.lo;
    *(short4v*)(whi + idx) = h;
    *(short4v*)(wlo + idx) = l;
}

// ---------------------------------------------------------------------------
// Embed split [k][e] + nhcc[k] = -0.5*||e_k||^2. Grid 64 x 256 (32 rows/blk).
// ---------------------------------------------------------------------------
__global__ void prep_kernel(const float* __restrict__ embed,
                            short* __restrict__ ehi, short* __restrict__ elo,
                            float* __restrict__ nhcc) {
    const int tid = threadIdx.x;
    const int row = blockIdx.x * 32 + (tid >> 3);
    const int c = (tid & 7) * 8;
    const float* src = embed + (size_t)row * 64 + c;
    short8 hv, lv;
    float s = 0.f;
#pragma unroll
    for (int j = 0; j < 8; ++j) {
        float v = src[j];
        s = fmaf(v, v, s);
        HiLo r = split_tr(v);
        hv[j] = r.hi; lv[j] = r.lo;
    }
    *(short8*)(ehi + (size_t)row * 64 + c) = hv;
    *(short8*)(elo + (size_t)row * 64 + c) = lv;
    s += __shfl_xor(s, 1, 64);
    s += __shfl_xor(s, 2, 64);
    s += __shfl_xor(s, 4, 64);
    if ((tid & 7) == 0) nhcc[row] = -0.5f * s;
}

// ---------------------------------------------------------------------------
// Projection via bf16-split MFMA: h^T tile D[e][t] = W[e][c] * x[c][t] (+bias)
// Block 256 thr (4 waves), tile 128 t x 64 e; K-chunks of 32 c. Grid (32,16).
// x staged fp32 in LDS (stride 132: frag column reads conflict-free); x frags
// split to bf16 hi/lo on the fly; W frags loaded pre-split from global (L2).
// Emits h_hi/h_lo [n][64] bf16 (vq A-frag layout) + ||h||^2 -> lossacc.
// ---------------------------------------------------------------------------
__global__ __launch_bounds__(256) void proj_kernel(
        const float* __restrict__ x,
        const short* __restrict__ whi, const short* __restrict__ wlo,
        const float* __restrict__ bias,
        short* __restrict__ h_hi, short* __restrict__ h_lo,
        float* __restrict__ lossacc) {
    __shared__ float xs[32 * 132];   // [c][t], stride 132

    const int tid = threadIdx.x;
    const int wave = tid >> 6, lane = tid & 63;
    const int row16 = lane & 15, quad = lane >> 4;
    const int t0 = blockIdx.x * 128;
    const int b  = blockIdx.y;
    const float* xb = x + (size_t)b * C_ * T_ + t0;

    f32x4 acc[2][4];
#pragma unroll
    for (int i = 0; i < 2; ++i)
#pragma unroll
        for (int j = 0; j < 4; ++j) acc[i][j] = (f32x4){0.f, 0.f, 0.f, 0.f};

    for (int c0 = 0; c0 < C_; c0 += 32) {
        // Stage x chunk [32 c][128 t], coalesced float4 loads + stores.
#pragma unroll
        for (int j = 0; j < 4; ++j) {
            int linear = j * 1024 + tid * 4;
            int cc = linear >> 7, tt = linear & 127;
            float4 v = *(const float4*)(xb + (size_t)(c0 + cc) * T_ + tt);
            *(float4*)(xs + cc * 132 + tt) = v;
        }
        __syncthreads();

        // B fragments (x): 2 t-tiles, column reads + hi/lo split.
        short8 bh[2], bl[2];
#pragma unroll
        for (int tt2 = 0; tt2 < 2; ++tt2) {
            int t = wave * 32 + tt2 * 16 + row16;
#pragma unroll
            for (int j = 0; j < 8; ++j) {
                float v = xs[(quad * 8 + j) * 132 + t];
                HiLo r = split_tr(v);
                bh[tt2][j] = r.hi; bl[tt2][j] = r.lo;
            }
        }

        // A fragments (W, pre-split) + MFMA (3-term split product).
#pragma unroll
        for (int et = 0; et < 4; ++et) {
            size_t aoff = (size_t)(et * 16 + row16) * C_ + c0 + quad * 8;
            short8 ah = *(const short8*)(whi + aoff);
            short8 al = *(const short8*)(wlo + aoff);
#pragma unroll
            for (int tt2 = 0; tt2 < 2; ++tt2) {
                acc[tt2][et] = __builtin_amdgcn_mfma_f32_16x16x32_bf16(ah, bh[tt2], acc[tt2][et], 0, 0, 0);
                acc[tt2][et] = __builtin_amdgcn_mfma_f32_16x16x32_bf16(al, bh[tt2], acc[tt2][et], 0, 0, 0);
                acc[tt2][et] = __builtin_amdgcn_mfma_f32_16x16x32_bf16(ah, bl[tt2], acc[tt2][et], 0, 0, 0);
            }
        }
        __syncthreads();
    }

    // Epilogue: bias, ||h||^2, split-store h.
    // D layout: col(t)=lane&15, row(e)=quad*4+reg.
    float hh = 0.f;
#pragma unroll
    for (int et = 0; et < 4; ++et) {
        float4 bv = *(const float4*)(bias + et * 16 + quad * 4);
#pragma unroll
        for (int tt2 = 0; tt2 < 2; ++tt2) {
            f32x4 a = acc[tt2][et];
            a[0] += bv.x; a[1] += bv.y; a[2] += bv.z; a[3] += bv.w;
            hh = fmaf(a[0], a[0], hh); hh = fmaf(a[1], a[1], hh);
            hh = fmaf(a[2], a[2], hh); hh = fmaf(a[3], a[3], hh);
            short4v hv, lv;
#pragma unroll
            for (int r = 0; r < 4; ++r) {
                HiLo sp = split_tr(a[r]);
                hv[r] = sp.hi; lv[r] = sp.lo;
            }
            size_t n = (size_t)b * T_ + t0 + wave * 32 + tt2 * 16 + row16;
            size_t off = n * 64 + et * 16 + quad * 4;
            *(short4v*)(h_hi + off) = hv;
            *(short4v*)(h_lo + off) = lv;
        }
    }
#pragma unroll
    for (int m = 1; m < 64; m <<= 1) hh += __shfl_xor(hh, m, 64);
    if (lane == 0) atomicAdd(lossacc, hh);
}

// ---------------------------------------------------------------------------
// VQ: argmax of (h.e - 0.5*||e||^2) via bf16-split MFMA. K-split x4.
// Grid (N/256, 4); block = 4 waves x 64 rows; each block scans 512 codewords
// in 4 chunks of 128 (XOR-swizzled LDS). Per-row block-best merged globally
// via packed-key atomicMin (key = order(-v)<<32 | idx; tie -> lowest idx).
// ---------------------------------------------------------------------------
__global__ __launch_bounds__(256, 4) void vq_kernel(
        const short* __restrict__ h_hi, const short* __restrict__ h_lo,
        const short* __restrict__ ehi, const short* __restrict__ elo,
        const float* __restrict__ nhcc, unsigned long long* __restrict__ keys) {
    __shared__ short es_hi[128 * 64];   // [k][e], 8-short groups XOR-swizzled by (k&7)
    __shared__ short es_lo[128 * 64];
    __shared__ float ccs[128];

    const int tid = threadIdx.x;
    const int wave = tid >> 6, lane = tid & 63;
    const int row16 = lane & 15, quad = lane >> 4;
    const int rs = row16 & 7;
    const int off0 = ((quad ^ rs) * 8);
    const int nw = blockIdx.x * 256 + wave * 64;
    const int kbase = blockIdx.y * 512;

    // A fragments: 4 row-tiles x 2 k-steps, hi+lo; in regs all kernel.
    short8 a_hi[4][2], a_lo[4][2];
#pragma unroll
    for (int rt = 0; rt < 4; ++rt)
#pragma unroll
        for (int ks = 0; ks < 2; ++ks) {
            size_t off = (size_t)(nw + rt * 16 + row16) * 64 + ks * 32 + quad * 8;
            a_hi[rt][ks] = *(const short8*)(h_hi + off);
            a_lo[rt][ks] = *(const short8*)(h_lo + off);
        }

    float vmax[4][4];
    int   vidx[4][4];
#pragma unroll
    for (int rt = 0; rt < 4; ++rt)
#pragma unroll
        for (int rg = 0; rg < 4; ++rg) { vmax[rt][rg] = -3.4e38f; vidx[rt][rg] = 0; }

    for (int kc = 0; kc < 4; ++kc) {
        const int k0 = kbase + kc * 128;
        // Stage codebook chunk, swizzled: group g at row r lands at g^(r&7).
#pragma unroll
        for (int it = 0; it < 4; ++it) {
            int idx = it * 256 + tid;
            int r = idx >> 3, g = idx & 7;
            int dst = r * 64 + (g ^ (r & 7)) * 8;
            *(short8*)(es_hi + dst) = *(const short8*)(ehi + (size_t)(k0 + r) * 64 + g * 8);
            *(short8*)(es_lo + dst) = *(const short8*)(elo + (size_t)(k0 + r) * 64 + g * 8);
        }
        if (tid < 32) *(f32x4*)(ccs + tid * 4) = *(const f32x4*)(nhcc + k0 + tid * 4);
        __syncthreads();

#pragma unroll
        for (int kt = 0; kt < 8; ++kt) {
            const int row = kt * 16 + row16;
            const float ci = ccs[row];
            const short* p = es_hi + row * 64;
            const short* q = es_lo + row * 64;
            short8 bh0 = *(const short8*)(p + off0);
            short8 bh1 = *(const short8*)(p + (off0 ^ 32));
            short8 bl0 = *(const short8*)(q + off0);
            short8 bl1 = *(const short8*)(q + (off0 ^ 32));
            const int kk = k0 + row;
#pragma unroll
            for (int rt = 0; rt < 4; ++rt) {
                f32x4 acc = {ci, ci, ci, ci};
                acc = __builtin_amdgcn_mfma_f32_16x16x32_bf16(a_hi[rt][0], bh0, acc, 0, 0, 0);
                acc = __builtin_amdgcn_mfma_f32_16x16x32_bf16(a_hi[rt][1], bh1, acc, 0, 0, 0);
                acc = __builtin_amdgcn_mfma_f32_16x16x32_bf16(a_lo[rt][0], bh0, acc, 0, 0, 0);
                acc = __builtin_amdgcn_mfma_f32_16x16x32_bf16(a_lo[rt][1], bh1, acc, 0, 0, 0);
                acc = __builtin_amdgcn_mfma_f32_16x16x32_bf16(a_hi[rt][0], bl0, acc, 0, 0, 0);
                acc = __builtin_amdgcn_mfma_f32_16x16x32_bf16(a_hi[rt][1], bl1, acc, 0, 0, 0);
#pragma unroll
                for (int rg = 0; rg < 4; ++rg) {
                    float v = acc[rg];
                    if (v > vmax[rt][rg]) { vmax[rt][rg] = v; vidx[rt][rg] = kk; }
                }
            }
        }
        __syncthreads();
    }

    // Reduce over the 16 col-lanes; emit packed key (min == argmin d, tie->low idx).
#pragma unroll
    for (int rt = 0; rt < 4; ++rt) {
#pragma unroll
        for (int rg = 0; rg < 4; ++rg) {
            float v = vmax[rt][rg];
            int ix = vidx[rt][rg];
#pragma unroll
            for (int m = 1; m < 16; m <<= 1) {
                float ov = __shfl_xor(v, m, 64);
                int   oi = __shfl_xor(ix, m, 64);
                if (ov > v || (ov == v && oi < ix)) { v = ov; ix = oi; }
            }
            if (row16 == 0) {
                unsigned um = __float_as_uint(v) ^ 0x80000000u;   // bits of m = -v
                unsigned ord = (um & 0x80000000u) ? ~um : (um | 0x80000000u);
                unsigned long long key = ((unsigned long long)ord << 32) | (unsigned)ix;
                atomicMin(&keys[nw + rt * 16 + quad * 4 + rg], key);
            }
        }
    }
}

// ---------------------------------------------------------------------------
// Gather + transpose + decode: out[b][e][t] = embed[idx][e]; also hist + loss.
// Grid (T/64, B) x 256 thr.
// ---------------------------------------------------------------------------
__global__ void gather_kernel(const float* __restrict__ embed,
                              const unsigned long long* __restrict__ keys,
                              float* __restrict__ out,
                              int* __restrict__ hist, float* __restrict__ lossacc) {
    __shared__ float tile[64 * 65];
    __shared__ int qs[64];
    const int tid = threadIdx.x;
    const int t0 = blockIdx.x * 64;
    const int b  = blockIdx.y;

    if (tid < 64) {
        unsigned long long key = keys[b * T_ + t0 + tid];
        int ix = (int)(unsigned)(key & 0xFFFFFFFFull);
        qs[tid] = ix;
        atomicAdd(&hist[ix], 1);
        unsigned ord = (unsigned)(key >> 32);
        unsigned um = (ord & 0x80000000u) ? (ord & 0x7FFFFFFFu) : ~ord;
        float m = __uint_as_float(um);          // m = min over k of (0.5cc - S)
        float s = 2.f * m;                       // d_min = cc - 2S = 2m
#pragma unroll
        for (int mm = 1; mm < 64; mm <<= 1) s += __shfl_xor(s, mm, 64);
        if (tid == 0) atomicAdd(lossacc, s);
    }
    __syncthreads();

    const int t_l = tid >> 2, eq = tid & 3;
    const float4* src = (const float4*)(embed + (size_t)qs[t_l] * 64 + eq * 16);
#pragma unroll
    for (int j = 0; j < 4; ++j) {
        float4 v = src[j];
        int e = eq * 16 + j * 4;
        tile[t_l * 65 + e + 0] = v.x;
        tile[t_l * 65 + e + 1] = v.y;
        tile[t_l * 65 + e + 2] = v.z;
        tile[t_l * 65 + e + 3] = v.w;
    }
    __syncthreads();

    const int tt = tid & 63;
#pragma unroll
    for (int j = 0; j < 16; ++j) {
        int e = j * 4 + (tid >> 6);
        out[((size_t)b * 64 + e) * T_ + t0 + tt] = tile[tt * 65 + e];
    }
}

// ---------------------------------------------------------------------------
// Finalize: loss, kldiv constant, log-perplexity.
// ---------------------------------------------------------------------------
__global__ void finalize_kernel(const int* __restrict__ hist,
                                const float* __restrict__ lossacc,
                                float* __restrict__ out) {
    __shared__ float red[4];
    const int tid = threadIdx.x;
    float s = 0.f;
    for (int k = tid; k < K_; k += 256) {
        float p = (float)hist[k] * (1.f / 65536.f);
        s -= p * logf(p + 1e-10f);
    }
#pragma unroll
    for (int m = 1; m < 64; m <<= 1) s += __shfl_xor(s, m, 64);
    if ((tid & 63) == 0) red[tid >> 6] = s;
    __syncthreads();
    if (tid == 0) {
        float lp = red[0] + red[1] + red[2] + red[3];
        out[ZQ_ELEMS] = 0.25f * lossacc[0] / (float)ZQ_ELEMS;    // loss
        out[ZQ_ELEMS + 17] = lp;                                  // log_perplexity
    }
    if (tid < 16) out[ZQ_ELEMS + 1 + tid] = logf(2048.f) * 4096.f;  // kldiv_r
}

// ---------------------------------------------------------------------------
extern "C" void kernel_launch(void* const* d_in, const int* in_sizes, int n_in,
                              void* d_out, int out_size, void* d_ws, size_t ws_size,
                              hipStream_t stream) {
    const float* x      = (const float*)d_in[0];
    const float* proj_w = (const float*)d_in[1];
    const float* proj_b = (const float*)d_in[2];
    const float* embed  = (const float*)d_in[3];
    float* out = (float*)d_out;
    char* ws = (char*)d_ws;

    short* h_hi = (short*)(ws + WS_HHI);
    short* h_lo = (short*)(ws + WS_HLO);
    short* e_hi = (short*)(ws + WS_EHI);
    short* e_lo = (short*)(ws + WS_ELO);
    float* nhcc = (float*)(ws + WS_NHCC);
    short* w_hi = (short*)(ws + WS_WHI);
    short* w_lo = (short*)(ws + WS_WLO);
    unsigned long long* keys = (unsigned long long*)(ws + WS_KEYS);
    int*   hist   = (int*)(ws + WS_HIST);
    float* lossac = (float*)(ws + WS_LOSS);

    // loss must be zero before proj (ws is poisoned 0xAA each launch).
    (void)hipMemsetAsync(ws + WS_LOSS, 0, sizeof(float), stream);

    wprep_kernel<<<32, 256, 0, stream>>>(proj_w, w_hi, w_lo);
    prep_kernel<<<64, 256, 0, stream>>>(embed, e_hi, e_lo, nhcc);
    proj_kernel<<<dim3(T_ / 128, B_), 256, 0, stream>>>(x, w_hi, w_lo, proj_b, h_hi, h_lo, lossac);

    // keys alias the W region: init AFTER proj's last read of w (stream-ordered).
    (void)hipMemsetAsync(ws + WS_KEYS, 0xFF, N_ * sizeof(unsigned long long), stream);

    vq_kernel<<<dim3(N_ / 256, 4), 256, 0, stream>>>(h_hi, h_lo, e_hi, e_lo, nhcc, keys);

    // hist aliases e_hi: zero AFTER vq's last codebook read (stream-ordered).
    (void)hipMemsetAsync(ws + WS_HIST, 0, K_ * sizeof(int), stream);

    gather_kernel<<<dim3(T_ / 64, B_), 256, 0, stream>>>(embed, keys, out, hist, lossac);
    finalize_kernel<<<1, 256, 0, stream>>>(hist, lossac, out);
}

// Round 5
// 309.061 us; speedup vs baseline: 1.3645x; 1.3645x over previous
//
#include <hip/hip_runtime.h>
#include <math.h>

// Problem constants (from reference)
#define B_ 16
#define T_ 4096
#define C_ 512
#define E_ 64
#define K_ 2048
#define N_ (B_*T_)          // 65536
#define ZQ_ELEMS 4194304    // B*E*T

typedef __attribute__((ext_vector_type(8))) short short8;
typedef __attribute__((ext_vector_type(4))) short short4v;
typedef __attribute__((ext_vector_type(4))) float f32x4;

// ws layout (bytes) — no aliasing this round:
//   e_hi : [K][64] bf16 @ 0        (256 KB)
//   e_lo : [K][64] bf16 @ 262144   (256 KB)
//   nhcc : [K] f32      @ 524288   (8 KB)    (-0.5*||e_k||^2)
//   w_hi : [64][512] bf16 @ 532480 (64 KB)
//   w_lo : [64][512] bf16 @ 598016 (64 KB)
//   qidx : [N] i32      @ 663552   (256 KB)
//   hist : [K] i32      @ 925696   (8 KB)    <- memset 0 with loss
//   loss : f32          @ 933888   (4 B)
#define WS_EHI   0
#define WS_ELO   262144
#define WS_NHCC  524288
#define WS_WHI   532480
#define WS_WLO   598016
#define WS_QIDX  663552
#define WS_HIST  925696
#define WS_LOSS  933888

struct HiLo { short hi, lo; };

__device__ __forceinline__ unsigned short rne16(float v) {
    unsigned u = __float_as_uint(v);
    return (unsigned short)((u + 0x7FFFu + ((u >> 16) & 1u)) >> 16);
}
// RNE-hi / RNE-lo split: hi = rne_bf16(v), lo = rne_bf16(v - hi). |lo| <~ 2^-9 |v|.
__device__ __forceinline__ HiLo split_rne(float v) {
    HiLo r;
    unsigned hb = rne16(v);
    r.hi = (short)hb;
    float hf = __uint_as_float((unsigned)hb << 16);
    r.lo = (short)rne16(v - hf);
    return r;
}

// ---------------------------------------------------------------------------
// Fused prep: blocks 0..63 -> embed split [k][e] + nhcc; blocks 64..95 -> W split.
// ---------------------------------------------------------------------------
__global__ void prep_kernel(const float* __restrict__ embed,
                            const float* __restrict__ W,
                            short* __restrict__ ehi, short* __restrict__ elo,
                            float* __restrict__ nhcc,
                            short* __restrict__ whi, short* __restrict__ wlo) {
    const int tid = threadIdx.x;
    if (blockIdx.x < 64) {
        const int row = blockIdx.x * 32 + (tid >> 3);
        const int c = (tid & 7) * 8;
        const float* src = embed + (size_t)row * 64 + c;
        short8 hv, lv;
        float s = 0.f;
#pragma unroll
        for (int j = 0; j < 8; ++j) {
            float v = src[j];
            s = fmaf(v, v, s);
            HiLo r = split_rne(v);
            hv[j] = r.hi; lv[j] = r.lo;
        }
        *(short8*)(ehi + (size_t)row * 64 + c) = hv;
        *(short8*)(elo + (size_t)row * 64 + c) = lv;
        s += __shfl_xor(s, 1, 64);
        s += __shfl_xor(s, 2, 64);
        s += __shfl_xor(s, 4, 64);
        if ((tid & 7) == 0) nhcc[row] = -0.5f * s;
    } else {
        int idx = ((blockIdx.x - 64) * 256 + tid) * 4;
        float4 v = *(const float4*)(W + idx);
        short4v h, l;
        HiLo a = split_rne(v.x); h[0] = a.hi; l[0] = a.lo;
        HiLo b = split_rne(v.y); h[1] = b.hi; l[1] = b.lo;
        HiLo c = split_rne(v.z); h[2] = c.hi; l[2] = c.lo;
        HiLo d = split_rne(v.w); h[3] = d.hi; l[3] = d.lo;
        *(short4v*)(whi + idx) = h;
        *(short4v*)(wlo + idx) = l;
    }
}

// ---------------------------------------------------------------------------
// Fused proj+VQ. Block = 256 thr (4 waves) handles 128 rows. Grid N/128 = 512.
// Phase 1 (proj): h[t][e] = W.x + bias via bf16-split 4-term MFMA (h ~ fp32-exact);
//                 x staged fp32 in LDS; W read pre-split from global (L2-resident).
// Phase 2 (vq):   h parked in LDS (hi/lo bf16), A-frags to regs (32 rows/wave),
//                 scan K=2048 in 16 chunks of 128 (XOR-swizzled LDS), 3-term MFMA,
//                 block-local argmax of (S - 0.5||e||^2) -> qidx/hist/loss direct.
// One 34.8 KB LDS buffer time-shared by all three stages -> 4 blocks/CU by LDS.
// ---------------------------------------------------------------------------
__global__ __launch_bounds__(256, 2) void projvq_kernel(
        const float* __restrict__ x,
        const short* __restrict__ whi, const short* __restrict__ wlo,
        const float* __restrict__ bias,
        const short* __restrict__ ehi, const short* __restrict__ elo,
        const float* __restrict__ nhcc,
        int* __restrict__ qidx, int* __restrict__ hist,
        float* __restrict__ lossacc) {
    __shared__ float smemf[8704];                 // 34816 B, time-shared
    float* xs = smemf;                            // [c][t] 32 x 136 f32 (17408 B)
    short* hT_hi = (short*)smemf;                 // [t][e] 128 x 68 bf16 (17408 B)
    short* hT_lo = hT_hi + 8704;                  //                      (17408 B)
    short* es_hi = (short*)smemf;                 // [k][e] 128 x 64, XOR-swizzled
    short* es_lo = es_hi + 8192;
    float* ccs   = (float*)(es_lo + 8192);        // [128]

    const int tid = threadIdx.x;
    const int wave = tid >> 6, lane = tid & 63;
    const int row16 = lane & 15, quad = lane >> 4;
    const int n0 = blockIdx.x * 128;
    const int b  = n0 / T_;
    const int t0 = n0 % T_;
    const float* xb = x + (size_t)b * C_ * T_ + t0;

    // ---------------- Phase 1: projection ----------------
    f32x4 acc[2][4];
#pragma unroll
    for (int i = 0; i < 2; ++i)
#pragma unroll
        for (int j = 0; j < 4; ++j) acc[i][j] = (f32x4){0.f, 0.f, 0.f, 0.f};

    for (int c0 = 0; c0 < C_; c0 += 32) {
        // Stage x chunk [32 c][128 t], stride 136 (B-frag col reads 2-way = free).
#pragma unroll
        for (int j = 0; j < 4; ++j) {
            int linear = j * 1024 + tid * 4;
            int cc = linear >> 7, tt = linear & 127;
            float4 v = *(const float4*)(xb + (size_t)(c0 + cc) * T_ + tt);
            *(float4*)(xs + cc * 136 + tt) = v;
        }
        __syncthreads();

        // B fragments (x): 2 t-tiles, column reads + RNE hi/lo split.
        short8 bh[2], bl[2];
#pragma unroll
        for (int tt2 = 0; tt2 < 2; ++tt2) {
            int t = wave * 32 + tt2 * 16 + row16;
#pragma unroll
            for (int j = 0; j < 8; ++j) {
                float v = xs[(quad * 8 + j) * 136 + t];
                HiLo r = split_rne(v);
                bh[tt2][j] = r.hi; bl[tt2][j] = r.lo;
            }
        }

        // A fragments (W, pre-split) + 4-term MFMA (h effectively fp32-exact).
#pragma unroll
        for (int et = 0; et < 4; ++et) {
            size_t aoff = (size_t)(et * 16 + row16) * C_ + c0 + quad * 8;
            short8 ah = *(const short8*)(whi + aoff);
            short8 al = *(const short8*)(wlo + aoff);
#pragma unroll
            for (int tt2 = 0; tt2 < 2; ++tt2) {
                acc[tt2][et] = __builtin_amdgcn_mfma_f32_16x16x32_bf16(ah, bh[tt2], acc[tt2][et], 0, 0, 0);
                acc[tt2][et] = __builtin_amdgcn_mfma_f32_16x16x32_bf16(al, bh[tt2], acc[tt2][et], 0, 0, 0);
                acc[tt2][et] = __builtin_amdgcn_mfma_f32_16x16x32_bf16(ah, bl[tt2], acc[tt2][et], 0, 0, 0);
                acc[tt2][et] = __builtin_amdgcn_mfma_f32_16x16x32_bf16(al, bl[tt2], acc[tt2][et], 0, 0, 0);
            }
        }
        __syncthreads();
    }

    // Epilogue: bias, ||h||^2 -> lossacc, split h into LDS [t][e] (stride 68).
    // D layout (m89): col(t)=lane&15, row(e)=quad*4+reg.
    float hh = 0.f;
#pragma unroll
    for (int et = 0; et < 4; ++et) {
        float4 bv = *(const float4*)(bias + et * 16 + quad * 4);
#pragma unroll
        for (int tt2 = 0; tt2 < 2; ++tt2) {
            f32x4 a = acc[tt2][et];
            a[0] += bv.x; a[1] += bv.y; a[2] += bv.z; a[3] += bv.w;
            hh = fmaf(a[0], a[0], hh); hh = fmaf(a[1], a[1], hh);
            hh = fmaf(a[2], a[2], hh); hh = fmaf(a[3], a[3], hh);
            short4v hv, lv;
#pragma unroll
            for (int r = 0; r < 4; ++r) {
                HiLo sp = split_rne(a[r]);
                hv[r] = sp.hi; lv[r] = sp.lo;
            }
            int t = wave * 32 + tt2 * 16 + row16;
            int e0 = et * 16 + quad * 4;
            *(short4v*)(hT_hi + t * 68 + e0) = hv;
            *(short4v*)(hT_lo + t * 68 + e0) = lv;
        }
    }
#pragma unroll
    for (int m = 1; m < 64; m <<= 1) hh += __shfl_xor(hh, m, 64);
    if (lane == 0) atomicAdd(lossacc, hh);
    __syncthreads();

    // ---------------- Phase 2: VQ ----------------
    // A fragments: 2 row-tiles x 2 k-steps, hi+lo -> registers for entire scan.
    short8 a_hi[2][2], a_lo[2][2];
#pragma unroll
    for (int rt = 0; rt < 2; ++rt)
#pragma unroll
        for (int ks = 0; ks < 2; ++ks) {
            int lr = wave * 32 + rt * 16 + row16;
            a_hi[rt][ks] = *(const short8*)(hT_hi + lr * 68 + ks * 32 + quad * 8);
            a_lo[rt][ks] = *(const short8*)(hT_lo + lr * 68 + ks * 32 + quad * 8);
        }
    __syncthreads();

    const int rs = row16 & 7;
    const int off0 = (quad ^ rs) * 8;

    float vmax[2][4];
    int   vidx[2][4];
#pragma unroll
    for (int rt = 0; rt < 2; ++rt)
#pragma unroll
        for (int rg = 0; rg < 4; ++rg) { vmax[rt][rg] = -3.4e38f; vidx[rt][rg] = 0; }

    for (int k0 = 0; k0 < K_; k0 += 128) {
        // Stage codebook chunk; e-group g of row r lands at g^(r&7) (0 conflicts, R4-proven).
#pragma unroll
        for (int it = 0; it < 4; ++it) {
            int idx = it * 256 + tid;
            int r = idx >> 3, g = idx & 7;
            int dst = r * 64 + (g ^ (r & 7)) * 8;
            *(short8*)(es_hi + dst) = *(const short8*)(ehi + (size_t)(k0 + r) * 64 + g * 8);
            *(short8*)(es_lo + dst) = *(const short8*)(elo + (size_t)(k0 + r) * 64 + g * 8);
        }
        if (tid < 32) *(f32x4*)(ccs + tid * 4) = *(const f32x4*)(nhcc + k0 + tid * 4);
        __syncthreads();

#pragma unroll
        for (int kt = 0; kt < 8; ++kt) {
            const int row = kt * 16 + row16;
            const float ci = ccs[row];
            const short* p = es_hi + row * 64;
            const short* q = es_lo + row * 64;
            short8 bh0 = *(const short8*)(p + off0);
            short8 bh1 = *(const short8*)(p + (off0 ^ 32));
            short8 bl0 = *(const short8*)(q + off0);
            short8 bl1 = *(const short8*)(q + (off0 ^ 32));
            const int kk = k0 + row;
#pragma unroll
            for (int rt = 0; rt < 2; ++rt) {
                f32x4 acc2 = {ci, ci, ci, ci};
                acc2 = __builtin_amdgcn_mfma_f32_16x16x32_bf16(a_hi[rt][0], bh0, acc2, 0, 0, 0);
                acc2 = __builtin_amdgcn_mfma_f32_16x16x32_bf16(a_hi[rt][1], bh1, acc2, 0, 0, 0);
                acc2 = __builtin_amdgcn_mfma_f32_16x16x32_bf16(a_lo[rt][0], bh0, acc2, 0, 0, 0);
                acc2 = __builtin_amdgcn_mfma_f32_16x16x32_bf16(a_lo[rt][1], bh1, acc2, 0, 0, 0);
                acc2 = __builtin_amdgcn_mfma_f32_16x16x32_bf16(a_hi[rt][0], bl0, acc2, 0, 0, 0);
                acc2 = __builtin_amdgcn_mfma_f32_16x16x32_bf16(a_hi[rt][1], bl1, acc2, 0, 0, 0);
#pragma unroll
                for (int rg = 0; rg < 4; ++rg) {
                    float v = acc2[rg];
                    if (v > vmax[rt][rg]) { vmax[rt][rg] = v; vidx[rt][rg] = kk; }
                }
            }
        }
        __syncthreads();
    }

    // Reduce over 16 col-lanes (tie -> lowest idx); emit qidx/hist/loss directly.
    float s = 0.f;
#pragma unroll
    for (int rt = 0; rt < 2; ++rt) {
#pragma unroll
        for (int rg = 0; rg < 4; ++rg) {
            float v = vmax[rt][rg];
            int ix = vidx[rt][rg];
#pragma unroll
            for (int m = 1; m < 16; m <<= 1) {
                float ov = __shfl_xor(v, m, 64);
                int   oi = __shfl_xor(ix, m, 64);
                if (ov > v || (ov == v && oi < ix)) { v = ov; ix = oi; }
            }
            if (row16 == 0) {
                int rown = n0 + wave * 32 + rt * 16 + quad * 4 + rg;
                qidx[rown] = ix;
                atomicAdd(&hist[ix], 1);
                s += v;
            }
        }
    }
    s += __shfl_xor(s, 16, 64);
    s += __shfl_xor(s, 32, 64);
    if (lane == 0) atomicAdd(lossacc, -2.f * s);   // sum of min d2 = -2*max(S-0.5cc)
}

// ---------------------------------------------------------------------------
// Gather + transpose: out[b][e][t] = embed[qidx[b*T+t]][e]  (fp32 exact)
// ---------------------------------------------------------------------------
__global__ void gather_kernel(const float* __restrict__ embed,
                              const int* __restrict__ qidx,
                              float* __restrict__ out) {
    __shared__ float tile[64 * 65];
    __shared__ int qs[64];
    const int tid = threadIdx.x;
    const int t0 = blockIdx.x * 64;
    const int b  = blockIdx.y;

    if (tid < 64) qs[tid] = qidx[b * T_ + t0 + tid];
    __syncthreads();

    const int t_l = tid >> 2, eq = tid & 3;
    const float4* src = (const float4*)(embed + (size_t)qs[t_l] * 64 + eq * 16);
#pragma unroll
    for (int j = 0; j < 4; ++j) {
        float4 v = src[j];
        int e = eq * 16 + j * 4;
        tile[t_l * 65 + e + 0] = v.x;
        tile[t_l * 65 + e + 1] = v.y;
        tile[t_l * 65 + e + 2] = v.z;
        tile[t_l * 65 + e + 3] = v.w;
    }
    __syncthreads();

    const int tt = tid & 63;
#pragma unroll
    for (int j = 0; j < 16; ++j) {
        int e = j * 4 + (tid >> 6);
        out[((size_t)b * 64 + e) * T_ + t0 + tt] = tile[tt * 65 + e];
    }
}

// ---------------------------------------------------------------------------
// Finalize: loss, kldiv constant, log-perplexity.
// ---------------------------------------------------------------------------
__global__ void finalize_kernel(const int* __restrict__ hist,
                                const float* __restrict__ lossacc,
                                float* __restrict__ out) {
    __shared__ float red[4];
    const int tid = threadIdx.x;
    float s = 0.f;
    for (int k = tid; k < K_; k += 256) {
        float p = (float)hist[k] * (1.f / 65536.f);
        s -= p * logf(p + 1e-10f);
    }
#pragma unroll
    for (int m = 1; m < 64; m <<= 1) s += __shfl_xor(s, m, 64);
    if ((tid & 63) == 0) red[tid >> 6] = s;
    __syncthreads();
    if (tid == 0) {
        float lp = red[0] + red[1] + red[2] + red[3];
        out[ZQ_ELEMS] = 0.25f * lossacc[0] / (float)ZQ_ELEMS;    // loss
        out[ZQ_ELEMS + 17] = lp;                                  // log_perplexity
    }
    if (tid < 16) out[ZQ_ELEMS + 1 + tid] = logf(2048.f) * 4096.f;  // kldiv_r
}

// ---------------------------------------------------------------------------
extern "C" void kernel_launch(void* const* d_in, const int* in_sizes, int n_in,
                              void* d_out, int out_size, void* d_ws, size_t ws_size,
                              hipStream_t stream) {
    const float* x      = (const float*)d_in[0];
    const float* proj_w = (const float*)d_in[1];
    const float* proj_b = (const float*)d_in[2];
    const float* embed  = (const float*)d_in[3];
    float* out = (float*)d_out;
    char* ws = (char*)d_ws;

    short* e_hi = (short*)(ws + WS_EHI);
    short* e_lo = (short*)(ws + WS_ELO);
    float* nhcc = (float*)(ws + WS_NHCC);
    short* w_hi = (short*)(ws + WS_WHI);
    short* w_lo = (short*)(ws + WS_WLO);
    int*   qidx = (int*)(ws + WS_QIDX);
    int*   hist = (int*)(ws + WS_HIST);
    float* lossac = (float*)(ws + WS_LOSS);

    // hist + loss are adjacent; zero both (ws is poisoned 0xAA each launch).
    (void)hipMemsetAsync(ws + WS_HIST, 0, K_ * sizeof(int) + sizeof(float), stream);

    prep_kernel<<<96, 256, 0, stream>>>(embed, proj_w, e_hi, e_lo, nhcc, w_hi, w_lo);
    projvq_kernel<<<N_ / 128, 256, 0, stream>>>(x, w_hi, w_lo, proj_b,
                                                e_hi, e_lo, nhcc, qidx, hist, lossac);
    gather_kernel<<<dim3(T_ / 64, B_), 256, 0, stream>>>(embed, qidx, out);
    finalize_kernel<<<1, 256, 0, stream>>>(hist, lossac, out);
}

// Round 6
// 305.461 us; speedup vs baseline: 1.3806x; 1.0118x over previous
//
#include <hip/hip_runtime.h>
#include <math.h>

// Problem constants (from reference)
#define B_ 16
#define T_ 4096
#define C_ 512
#define E_ 64
#define K_ 2048
#define N_ (B_*T_)          // 65536
#define ZQ_ELEMS 4194304    // B*E*T

typedef __attribute__((ext_vector_type(8))) short short8;
typedef __attribute__((ext_vector_type(4))) short short4v;
typedef __attribute__((ext_vector_type(4))) float f32x4;

// ws layout (bytes):
//   ehi_sw : [16][8192] bf16 B-frag-tiled codebook hi @ 0       (256 KB)
//   elo_sw : lo plane                              @ 262144     (256 KB)
//   nhcc   : [K] f32 (-0.5*||e_k||^2)              @ 524288     (8 KB)
//   w_hi   : [64][512] bf16                        @ 532480     (64 KB)
//   w_lo   : [64][512] bf16                        @ 598016     (64 KB)
//   hist   : [K] i32                               @ 663552     (8 KB)  <- memset w/ loss
//   loss   : f32                                   @ 671744     (4 B)
#define WS_EHI   0
#define WS_ELO   262144
#define WS_NHCC  524288
#define WS_WHI   532480
#define WS_WLO   598016
#define WS_HIST  663552
#define WS_LOSS  671744

struct HiLo { short hi, lo; };

__device__ __forceinline__ unsigned short rne16(float v) {
    unsigned u = __float_as_uint(v);
    return (unsigned short)((u + 0x7FFFu + ((u >> 16) & 1u)) >> 16);
}
__device__ __forceinline__ HiLo split_rne(float v) {
    HiLo r;
    unsigned hb = rne16(v);
    r.hi = (short)hb;
    float hf = __uint_as_float((unsigned)hb << 16);
    r.lo = (short)rne16(v - hf);
    return r;
}

// ---------------------------------------------------------------------------
// Prep. Blocks 0..63: embed -> B-frag-tiled bf16 hi/lo + nhcc.
//       Blocks 64..95: W -> flat bf16 hi/lo.
// Tiled layout per 128-k chunk (8192 shorts/plane): slot for (r=k&127, e):
//   kt=r>>4, col=r&15, ks=e>>5, qe=(e>>3)&3 -> ((kt*2+ks)*64 + qe*16 + col)*8 + (e&7)
// so projvq staging is a linear copy and ds_read is base + lane*16.
// ---------------------------------------------------------------------------
__global__ void prep_kernel(const float* __restrict__ embed,
                            const float* __restrict__ W,
                            short* __restrict__ ehi, short* __restrict__ elo,
                            float* __restrict__ nhcc,
                            short* __restrict__ whi, short* __restrict__ wlo) {
    const int tid = threadIdx.x;
    if (blockIdx.x < 64) {
        const int row = blockIdx.x * 32 + (tid >> 3);
        const int g = tid & 7;
        const float* src = embed + (size_t)row * 64 + g * 8;
        short8 hv, lv;
        float s = 0.f;
#pragma unroll
        for (int j = 0; j < 8; ++j) {
            float v = src[j];
            s = fmaf(v, v, s);
            HiLo r = split_rne(v);
            hv[j] = r.hi; lv[j] = r.lo;
        }
        const int c128 = row >> 7, r = row & 127;
        const int kt = r >> 4, col = r & 15, ks = g >> 2, qe = g & 3;
        const int slot = (kt * 2 + ks) * 64 + qe * 16 + col;
        *(short8*)(ehi + c128 * 8192 + slot * 8) = hv;
        *(short8*)(elo + c128 * 8192 + slot * 8) = lv;
        s += __shfl_xor(s, 1, 64);
        s += __shfl_xor(s, 2, 64);
        s += __shfl_xor(s, 4, 64);
        if (g == 0) nhcc[row] = -0.5f * s;
    } else {
        int idx = ((blockIdx.x - 64) * 256 + tid) * 4;
        float4 v = *(const float4*)(W + idx);
        short4v h, l;
        HiLo a = split_rne(v.x); h[0] = a.hi; l[0] = a.lo;
        HiLo b = split_rne(v.y); h[1] = b.hi; l[1] = b.lo;
        HiLo c = split_rne(v.z); h[2] = c.hi; l[2] = c.lo;
        HiLo d = split_rne(v.w); h[3] = d.hi; l[3] = d.lo;
        *(short4v*)(whi + idx) = h;
        *(short4v*)(wlo + idx) = l;
    }
}

// ---------------------------------------------------------------------------
// Fused proj + VQ + gather. Block 256 thr (4 waves) = 128 rows. Grid 512.
// Phase 1: h = W.x + bias, bf16-split 4-term MFMA; x reg-prefetched into LDS.
// Park:    h split to bf16 hi/lo in A-frag-ordered LDS image (lane-linear).
// Phase 2: scan K=2048 in 16 chunks of 128; codebook reg-prefetched, staged
//          by LINEAR copy (pre-tiled in prep); all ds_read_b128 lane-linear
//          (conflict-free); 3-term MFMA; block-local argmax.
// Phase 3: block writes its own z_q rows (gather fused; no qidx round-trip).
// ---------------------------------------------------------------------------
__global__ __launch_bounds__(256, 2) void projvq_kernel(
        const float* __restrict__ x,
        const short* __restrict__ whi, const short* __restrict__ wlo,
        const float* __restrict__ bias,
        const short* __restrict__ ehi, const short* __restrict__ elo,
        const float* __restrict__ nhcc,
        const float* __restrict__ embed, float* __restrict__ out,
        int* __restrict__ hist, float* __restrict__ lossacc) {
    __shared__ float smemf[8832];                 // 35328 B peak (phase-3 tile)
    float* xs   = smemf;                          // [c][t] 32 x 136 f32
    short* aimg = (short*)smemf;                  // A-frag image hi@0, lo@8192 (shorts)
    short* es   = (short*)smemf;                  // codebook hi@0, lo@8192 (shorts)
    float* ccs  = (float*)(smemf + 8192);         // 128 f32 @ byte 32768
    float* tile = smemf;                          // phase 3: 128 x 69 f32
    __shared__ int qs[128];

    const int tid = threadIdx.x;
    const int wave = tid >> 6, lane = tid & 63;
    const int row16 = lane & 15, quad = lane >> 4;
    const int b  = blockIdx.x >> 5;
    const int t0 = (blockIdx.x & 31) * 128;
    const float* xb = x + (size_t)b * C_ * T_ + t0;

    // nhcc -> regs once (8 f32/thread), redistributed to LDS per chunk.
    f32x4 cc0 = *(const f32x4*)(nhcc + tid * 8);
    f32x4 cc1 = *(const f32x4*)(nhcc + tid * 8 + 4);

    // ---------------- Phase 1: projection ----------------
    f32x4 acc[2][4];
#pragma unroll
    for (int i = 0; i < 2; ++i)
#pragma unroll
        for (int j = 0; j < 4; ++j) acc[i][j] = (f32x4){0.f, 0.f, 0.f, 0.f};

    const int xcc = tid >> 5;            // this thread's c-row within chunk (j adds 8)
    const int xtt = (tid & 31) * 4;      // t offset
    float4 xpf[4];
#pragma unroll
    for (int j = 0; j < 4; ++j)
        xpf[j] = *(const float4*)(xb + (size_t)(xcc + j * 8) * T_ + xtt);

    for (int c0 = 0; c0 < C_; c0 += 32) {
#pragma unroll
        for (int j = 0; j < 4; ++j)
            *(float4*)(xs + (xcc + j * 8) * 136 + xtt) = xpf[j];
        __syncthreads();
        if (c0 < C_ - 32) {
#pragma unroll
            for (int j = 0; j < 4; ++j)
                xpf[j] = *(const float4*)(xb + (size_t)(c0 + 32 + xcc + j * 8) * T_ + xtt);
        }

        short8 bh[2], bl[2];
#pragma unroll
        for (int tt2 = 0; tt2 < 2; ++tt2) {
            int t = wave * 32 + tt2 * 16 + row16;
#pragma unroll
            for (int j = 0; j < 8; ++j) {
                float v = xs[(quad * 8 + j) * 136 + t];
                HiLo r = split_rne(v);
                bh[tt2][j] = r.hi; bl[tt2][j] = r.lo;
            }
        }
#pragma unroll
        for (int et = 0; et < 4; ++et) {
            size_t aoff = (size_t)(et * 16 + row16) * C_ + c0 + quad * 8;
            short8 ah = *(const short8*)(whi + aoff);
            short8 al = *(const short8*)(wlo + aoff);
#pragma unroll
            for (int tt2 = 0; tt2 < 2; ++tt2) {
                acc[tt2][et] = __builtin_amdgcn_mfma_f32_16x16x32_bf16(ah, bh[tt2], acc[tt2][et], 0, 0, 0);
                acc[tt2][et] = __builtin_amdgcn_mfma_f32_16x16x32_bf16(al, bh[tt2], acc[tt2][et], 0, 0, 0);
                acc[tt2][et] = __builtin_amdgcn_mfma_f32_16x16x32_bf16(ah, bl[tt2], acc[tt2][et], 0, 0, 0);
                acc[tt2][et] = __builtin_amdgcn_mfma_f32_16x16x32_bf16(al, bl[tt2], acc[tt2][et], 0, 0, 0);
            }
        }
        __syncthreads();
    }

    // Epilogue: bias, ||h||^2, park h in A-frag image (2-way LDS = free).
    // D layout: col(t)=lane&15, row(e)=quad*4+reg. rt == tt2 for t=wave*32+tt2*16+row16.
    float hh = 0.f;
#pragma unroll
    for (int et = 0; et < 4; ++et) {
        float4 bv = *(const float4*)(bias + et * 16 + quad * 4);
#pragma unroll
        for (int tt2 = 0; tt2 < 2; ++tt2) {
            f32x4 a = acc[tt2][et];
            a[0] += bv.x; a[1] += bv.y; a[2] += bv.z; a[3] += bv.w;
            hh = fmaf(a[0], a[0], hh); hh = fmaf(a[1], a[1], hh);
            hh = fmaf(a[2], a[2], hh); hh = fmaf(a[3], a[3], hh);
            short4v hv, lv;
#pragma unroll
            for (int r = 0; r < 4; ++r) {
                HiLo sp = split_rne(a[r]);
                hv[r] = sp.hi; lv[r] = sp.lo;
            }
            const int ks = et >> 1;
            const int qe = (et & 1) * 2 + (quad >> 1);
            const int j0 = (quad & 1) * 4;
            const int sl = (((wave * 2 + tt2) * 2 + ks) * 64 + qe * 16 + row16) * 8 + j0;
            *(short4v*)(aimg + sl) = hv;
            *(short4v*)(aimg + 8192 + sl) = lv;
        }
    }
#pragma unroll
    for (int m = 1; m < 64; m <<= 1) hh += __shfl_xor(hh, m, 64);
    if (lane == 0) atomicAdd(lossacc, hh);
    __syncthreads();

    // ---------------- Phase 2: VQ ----------------
    // A-frags: lane-linear reads from the image -> regs for the whole scan.
    short8 a_hi[2][2], a_lo[2][2];
#pragma unroll
    for (int rt = 0; rt < 2; ++rt)
#pragma unroll
        for (int ks = 0; ks < 2; ++ks) {
            int sl = (((wave * 2 + rt) * 2 + ks) * 64 + lane) * 8;
            a_hi[rt][ks] = *(const short8*)(aimg + sl);
            a_lo[rt][ks] = *(const short8*)(aimg + 8192 + sl);
        }
    __syncthreads();

    // Prefetch codebook chunk 0 into regs.
    short8 pf[8];
#pragma unroll
    for (int it = 0; it < 4; ++it) {
        pf[it]     = *(const short8*)(ehi + (it * 256 + tid) * 8);
        pf[4 + it] = *(const short8*)(elo + (it * 256 + tid) * 8);
    }

    float vmax[2][4];
    int   vidx[2][4];
#pragma unroll
    for (int rt = 0; rt < 2; ++rt)
#pragma unroll
        for (int rg = 0; rg < 4; ++rg) { vmax[rt][rg] = -3.4e38f; vidx[rt][rg] = 0; }

    for (int c = 0; c < 16; ++c) {
        // Linear staged write (lane-linear, conflict-free).
#pragma unroll
        for (int it = 0; it < 4; ++it) {
            *(short8*)(es + (it * 256 + tid) * 8)        = pf[it];
            *(short8*)(es + 8192 + (it * 256 + tid) * 8) = pf[4 + it];
        }
        if ((tid >> 4) == c) {
            int u = tid & 15;
            *(f32x4*)(ccs + u * 8)     = cc0;
            *(f32x4*)(ccs + u * 8 + 4) = cc1;
        }
        __syncthreads();
        if (c < 15) {
            const short* sh = ehi + (c + 1) * 8192;
            const short* sl2 = elo + (c + 1) * 8192;
#pragma unroll
            for (int it = 0; it < 4; ++it) {
                pf[it]     = *(const short8*)(sh + (it * 256 + tid) * 8);
                pf[4 + it] = *(const short8*)(sl2 + (it * 256 + tid) * 8);
            }
        }

#pragma unroll
        for (int kt = 0; kt < 8; ++kt) {
            const float ci = ccs[kt * 16 + row16];
            const short* pb = es + (kt * 2) * 512;
            short8 bh0 = *(const short8*)(pb + lane * 8);
            short8 bh1 = *(const short8*)(pb + 512 + lane * 8);
            short8 bl0 = *(const short8*)(pb + 8192 + lane * 8);
            short8 bl1 = *(const short8*)(pb + 8192 + 512 + lane * 8);
            const int kk = c * 128 + kt * 16 + row16;
#pragma unroll
            for (int rt = 0; rt < 2; ++rt) {
                f32x4 a2 = {0.f, 0.f, 0.f, 0.f};
                a2 = __builtin_amdgcn_mfma_f32_16x16x32_bf16(a_hi[rt][0], bh0, a2, 0, 0, 0);
                a2 = __builtin_amdgcn_mfma_f32_16x16x32_bf16(a_hi[rt][1], bh1, a2, 0, 0, 0);
                a2 = __builtin_amdgcn_mfma_f32_16x16x32_bf16(a_lo[rt][0], bh0, a2, 0, 0, 0);
                a2 = __builtin_amdgcn_mfma_f32_16x16x32_bf16(a_lo[rt][1], bh1, a2, 0, 0, 0);
                a2 = __builtin_amdgcn_mfma_f32_16x16x32_bf16(a_hi[rt][0], bl0, a2, 0, 0, 0);
                a2 = __builtin_amdgcn_mfma_f32_16x16x32_bf16(a_hi[rt][1], bl1, a2, 0, 0, 0);
#pragma unroll
                for (int rg = 0; rg < 4; ++rg) {
                    float v = a2[rg] + ci;
                    if (v > vmax[rt][rg]) { vmax[rt][rg] = v; vidx[rt][rg] = kk; }
                }
            }
        }
        __syncthreads();
    }

    // Argmax reduce over 16 col-lanes (tie -> lowest idx); qs/hist/loss.
    float s = 0.f;
#pragma unroll
    for (int rt = 0; rt < 2; ++rt) {
#pragma unroll
        for (int rg = 0; rg < 4; ++rg) {
            float v = vmax[rt][rg];
            int ix = vidx[rt][rg];
#pragma unroll
            for (int m = 1; m < 16; m <<= 1) {
                float ov = __shfl_xor(v, m, 64);
                int   oi = __shfl_xor(ix, m, 64);
                if (ov > v || (ov == v && oi < ix)) { v = ov; ix = oi; }
            }
            if (row16 == 0) {
                qs[wave * 32 + rt * 16 + quad * 4 + rg] = ix;
                atomicAdd(&hist[ix], 1);
                s += v;
            }
        }
    }
    s += __shfl_xor(s, 16, 64);
    s += __shfl_xor(s, 32, 64);
    if (lane == 0) atomicAdd(lossacc, -2.f * s);
    __syncthreads();

    // ---------------- Phase 3: fused gather + transpose ----------------
    {
        const int r = tid >> 1, piece = tid & 1;
        const float* src = embed + (size_t)qs[r] * 64 + piece * 32;
#pragma unroll
        for (int j = 0; j < 8; ++j) {
            float4 v = *(const float4*)(src + j * 4);
            *(float4*)(tile + r * 69 + piece * 32 + j * 4) = v;
        }
    }
    __syncthreads();
    {
        const int tt = tid & 63;
        const int eo = tid >> 6;
        float* ob = out + ((size_t)b * 64) * T_ + t0;
#pragma unroll
        for (int j = 0; j < 16; ++j) {
            int e = j * 4 + eo;
            ob[(size_t)e * T_ + tt]      = tile[tt * 69 + e];
            ob[(size_t)e * T_ + 64 + tt] = tile[(tt + 64) * 69 + e];
        }
    }
}

// ---------------------------------------------------------------------------
// Finalize: loss, kldiv constant, log-perplexity.
// ---------------------------------------------------------------------------
__global__ void finalize_kernel(const int* __restrict__ hist,
                                const float* __restrict__ lossacc,
                                float* __restrict__ out) {
    __shared__ float red[4];
    const int tid = threadIdx.x;
    float s = 0.f;
    for (int k = tid; k < K_; k += 256) {
        float p = (float)hist[k] * (1.f / 65536.f);
        s -= p * logf(p + 1e-10f);
    }
#pragma unroll
    for (int m = 1; m < 64; m <<= 1) s += __shfl_xor(s, m, 64);
    if ((tid & 63) == 0) red[tid >> 6] = s;
    __syncthreads();
    if (tid == 0) {
        float lp = red[0] + red[1] + red[2] + red[3];
        out[ZQ_ELEMS] = 0.25f * lossacc[0] / (float)ZQ_ELEMS;    // loss
        out[ZQ_ELEMS + 17] = lp;                                  // log_perplexity
    }
    if (tid < 16) out[ZQ_ELEMS + 1 + tid] = logf(2048.f) * 4096.f;  // kldiv_r
}

// ---------------------------------------------------------------------------
extern "C" void kernel_launch(void* const* d_in, const int* in_sizes, int n_in,
                              void* d_out, int out_size, void* d_ws, size_t ws_size,
                              hipStream_t stream) {
    const float* x      = (const float*)d_in[0];
    const float* proj_w = (const float*)d_in[1];
    const float* proj_b = (const float*)d_in[2];
    const float* embed  = (const float*)d_in[3];
    float* out = (float*)d_out;
    char* ws = (char*)d_ws;

    short* e_hi = (short*)(ws + WS_EHI);
    short* e_lo = (short*)(ws + WS_ELO);
    float* nhcc = (float*)(ws + WS_NHCC);
    short* w_hi = (short*)(ws + WS_WHI);
    short* w_lo = (short*)(ws + WS_WLO);
    int*   hist = (int*)(ws + WS_HIST);
    float* lossac = (float*)(ws + WS_LOSS);

    // hist + loss adjacent; zero both (ws poisoned 0xAA each launch).
    (void)hipMemsetAsync(ws + WS_HIST, 0, K_ * sizeof(int) + sizeof(float), stream);

    prep_kernel<<<96, 256, 0, stream>>>(embed, proj_w, e_hi, e_lo, nhcc, w_hi, w_lo);
    projvq_kernel<<<N_ / 128, 256, 0, stream>>>(x, w_hi, w_lo, proj_b,
                                                e_hi, e_lo, nhcc, embed, out,
                                                hist, lossac);
    finalize_kernel<<<1, 256, 0, stream>>>(hist, lossac, out);
}